// Round 1
// baseline (5572.888 us; speedup 1.0000x reference)
//
#include <hip/hip_runtime.h>

#define NB 4
#define NM 80
#define NT 65536
#define NR 64
#define ND 64
#define NS 64
#define NL 20

__device__ __forceinline__ float fast_tanh(float v) {
    // tanh(v) = 1 - 2/(exp(2v)+1); exact saturation at +-inf, ~1e-7 rel error
    float e = __expf(2.0f * v);
    return 1.0f - 2.0f / (e + 1.0f);
}

extern "C" __global__ void __launch_bounds__(256, 2)
wavenet_fp32_kernel(const float* __restrict__ x,
                    const float* __restrict__ wc, const float* __restrict__ bc,
                    const float* __restrict__ wd, const float* __restrict__ bd,
                    const float* __restrict__ wr, const float* __restrict__ br,
                    const float* __restrict__ ws, const float* __restrict__ bs,
                    const float* __restrict__ w1, const float* __restrict__ b1,
                    const float* __restrict__ w2, const float* __restrict__ b2,
                    float* __restrict__ out)
{
    const int col = blockIdx.x * 256 + threadIdx.x;   // 0 .. B*T-1
    const int b   = col >> 16;                        // T = 65536
    const int t   = col & (NT - 1);
    const float* xc = x + ((size_t)b * NM) * NT + t;  // x[b][m][t] = xc[m*NT]

    // ---- causal 1x1 conv: h[r] = bc[r] + sum_m wc[r][m] * x[m] ----
    float h[NR];
#pragma unroll
    for (int r = 0; r < NR; ++r) h[r] = bc[r];

#pragma unroll
    for (int mt = 0; mt < NM; mt += 16) {
        float xv[16];
#pragma unroll
        for (int i = 0; i < 16; ++i)
            xv[i] = xc[(size_t)(mt + i) * NT];
#pragma unroll
        for (int r = 0; r < NR; ++r) {
            float acc = h[r];
#pragma unroll
            for (int i = 0; i < 16; ++i)
                acc = fmaf(wc[r * NM + mt + i], xv[i], acc);
            h[r] = acc;
        }
    }

    float skip[NS];
#pragma unroll
    for (int s = 0; s < NS; ++s) skip[s] = 0.0f;

    // ---- 20 residual layers (layer loop rolled; inner loops unrolled) ----
    for (int l = 0; l < NL; ++l) {
        const float* wdl = wd + (size_t)l * ND * NR;
        const float* bdl = bd + (size_t)l * ND;
        const float* wrl = wr + (size_t)l * NR * ND;
        const float* brl = br + (size_t)l * NR;
        const float* wsl = ws + (size_t)l * NS * ND;
        const float* bsl = bs + (size_t)l * NS;

        // f[d] = tanh(bd[d] + sum_r wd[d][r] * h[r])
        float f[ND];
#pragma unroll
        for (int d = 0; d < ND; d += 4) {
            float acc[4];
#pragma unroll
            for (int j = 0; j < 4; ++j) acc[j] = bdl[d + j];
#pragma unroll
            for (int r = 0; r < NR; ++r) {
                const float hv = h[r];
#pragma unroll
                for (int j = 0; j < 4; ++j)
                    acc[j] = fmaf(wdl[(d + j) * NR + r], hv, acc[j]);
            }
#pragma unroll
            for (int j = 0; j < 4; ++j) f[d + j] = fast_tanh(acc[j]);
        }

        // skip[s] += bs[s] + sum_d ws[s][d] * f[d]
#pragma unroll
        for (int s = 0; s < NS; s += 4) {
            float acc[4];
#pragma unroll
            for (int j = 0; j < 4; ++j) acc[j] = 0.0f;
#pragma unroll
            for (int d = 0; d < ND; ++d) {
                const float fv = f[d];
#pragma unroll
                for (int j = 0; j < 4; ++j)
                    acc[j] = fmaf(wsl[(s + j) * ND + d], fv, acc[j]);
            }
#pragma unroll
            for (int j = 0; j < 4; ++j)
                skip[s + j] += acc[j] + bsl[s + j];
        }

        // h[r] += br[r] + sum_d wr[r][d] * f[d]
#pragma unroll
        for (int r = 0; r < NR; r += 4) {
            float acc[4];
#pragma unroll
            for (int j = 0; j < 4; ++j) acc[j] = 0.0f;
#pragma unroll
            for (int d = 0; d < ND; ++d) {
                const float fv = f[d];
#pragma unroll
                for (int j = 0; j < 4; ++j)
                    acc[j] = fmaf(wrl[(r + j) * ND + d], fv, acc[j]);
            }
#pragma unroll
            for (int j = 0; j < 4; ++j)
                h[r + j] += acc[j] + brl[r + j];
        }
    }

    // ---- post net ----
    // s = tanh(skip_sum)
#pragma unroll
    for (int s = 0; s < NS; ++s) skip[s] = fast_tanh(skip[s]);

    // s2 = tanh(w1 @ s + b1)
    float s2[NS];
#pragma unroll
    for (int o = 0; o < NS; o += 4) {
        float acc[4];
#pragma unroll
        for (int j = 0; j < 4; ++j) acc[j] = b1[o + j];
#pragma unroll
        for (int s = 0; s < NS; ++s) {
            const float sv = skip[s];
#pragma unroll
            for (int j = 0; j < 4; ++j)
                acc[j] = fmaf(w1[(o + j) * NS + s], sv, acc[j]);
        }
#pragma unroll
        for (int j = 0; j < 4; ++j) s2[o + j] = fast_tanh(acc[j]);
    }

    // out = w2 @ s2 + b2   (single output channel)
    float p0 = 0.0f, p1 = 0.0f, p2 = 0.0f, p3 = 0.0f;
#pragma unroll
    for (int s = 0; s < NS; s += 4) {
        p0 = fmaf(w2[s + 0], s2[s + 0], p0);
        p1 = fmaf(w2[s + 1], s2[s + 1], p1);
        p2 = fmaf(w2[s + 2], s2[s + 2], p2);
        p3 = fmaf(w2[s + 3], s2[s + 3], p3);
    }
    out[col] = b2[0] + ((p0 + p1) + (p2 + p3));
}

extern "C" void kernel_launch(void* const* d_in, const int* in_sizes, int n_in,
                              void* d_out, int out_size, void* d_ws, size_t ws_size,
                              hipStream_t stream) {
    const float* x  = (const float*)d_in[0];
    const float* wc = (const float*)d_in[1];
    const float* bc = (const float*)d_in[2];
    const float* wd = (const float*)d_in[3];
    const float* bd = (const float*)d_in[4];
    const float* wr = (const float*)d_in[5];
    const float* br = (const float*)d_in[6];
    const float* ws = (const float*)d_in[7];
    const float* bs = (const float*)d_in[8];
    const float* w1 = (const float*)d_in[9];
    const float* b1 = (const float*)d_in[10];
    const float* w2 = (const float*)d_in[11];
    const float* b2 = (const float*)d_in[12];
    float* out = (float*)d_out;

    dim3 grid((NB * NT) / 256);
    dim3 block(256);
    hipLaunchKernelGGL(wavenet_fp32_kernel, grid, block, 0, stream,
                       x, wc, bc, wd, bd, wr, br, ws, bs, w1, b1, w2, b2, out);
}